// Round 1
// baseline (427.225 us; speedup 1.0000x reference)
//
#include <hip/hip_runtime.h>

// PixelWiseRNN: h_t = tanh(w_ih*x_t + (b_ih+b_hh) + w_hh*h_{t-1}), h_0 = 0
// x, out: (B=4, T=256, Z=16, H=64, W=64) fp32. Params: (Z,H,W) fp32.
//
// Roofline: 256 MiB read + 256 MiB write + 1 MiB params ~= 537 MB
//   -> ~85-95 us floor at 6.3 TB/s. Harness-verified R2: 427.2 us (~1.26 TB/s).
// R1 post-mortem: latency-bound (VALUBusy 25%, Occ 11%).
// R2: float2/thread (131072 threads -> 8 waves/CU), 8-deep rotating prefetch,
//     exp2-based tanh, nontemporal x/out.
// R3 (this round): prefetch depth 8 -> 16. Little's law: 6.3 TB/s * 375 ns
//     needs ~9.2 KB/CU in flight; nominal was 32 KB/CU but vmcnt is a single
//     in-order counter shared with the nt-stores, so effective depth may be
//     far lower. 16-deep doubles nominal in-flight to 64 KB/CU for +16 VGPR
//     and no occupancy change. Prediction: dur <=300 us if concurrency-bound;
//     unchanged if 512B/wave granularity or R/W turnaround is the limiter.

#define RNN_B   4
#define RNN_T   256
#define RNN_ZHW 65536                 // 16*64*64
#define RNN_PG2 (RNN_ZHW / 2)         // float2 groups per image: 32768
#define PF_D    16                    // prefetch depth (T % PF_D == 0)

typedef float f32x2 __attribute__((ext_vector_type(2)));

__device__ __forceinline__ float fast_tanh(float x) {
    // tanh(x) = 1 - 2/(exp(2x)+1), exp(2x) = 2^(2*log2(e)*x)
    // Saturation: x->+inf: exp->inf, rcp->0, result 1. x->-inf: exp->0, result -1.
    float e = __builtin_amdgcn_exp2f(x * 2.885390081777927f);
    float r = __builtin_amdgcn_rcpf(e + 1.0f);
    return fmaf(-2.0f, r, 1.0f);
}

__global__ __launch_bounds__(256) void pixel_rnn_kernel(
    const float* __restrict__ x,
    const float* __restrict__ w_ih,
    const float* __restrict__ w_hh,
    const float* __restrict__ b_ih,
    const float* __restrict__ b_hh,
    float* __restrict__ out)
{
    const int g  = blockIdx.x * 256 + threadIdx.x;   // [0, B*PG2) = [0, 131072)
    const int b  = g >> 15;                          // g / RNN_PG2
    const int pg = g & (RNN_PG2 - 1);                // float2-group within image
    const int p  = pg << 1;                          // first float index

    // Per-pixel parameters (1 MB total, L2/LLC-resident; normal cached loads).
    const f32x2 wi = *(const f32x2*)(w_ih + p);
    const f32x2 wh = *(const f32x2*)(w_hh + p);
    const f32x2 bi = *(const f32x2*)(b_ih + p);
    const f32x2 bh = *(const f32x2*)(b_hh + p);
    const float bias_x = bi.x + bh.x;
    const float bias_y = bi.y + bh.y;

    // Lanes are consecutive pg -> 512 B contiguous per wave load. Blocks never
    // straddle b (32768 % 256 == 0).
    const f32x2* __restrict__ xp = (const f32x2*)x + (size_t)b * (RNN_T * RNN_PG2) + pg;
    f32x2* __restrict__ op       = (f32x2*)out     + (size_t)b * (RNN_T * RNN_PG2) + pg;

    float hx = 0.f, hy = 0.f;

    // 16-deep rotating prefetch: buf[j] holds x_{t+j}; each unrolled step
    // consumes buf[j] and issues the load for t+j+PF_D (clamped; the few
    // redundant tail loads hit L2). 16 loads + stores in flight per wave.
    f32x2 buf[PF_D];
#pragma unroll
    for (int j = 0; j < PF_D; ++j)
        buf[j] = __builtin_nontemporal_load(xp + (size_t)j * RNN_PG2);

    for (int t = 0; t < RNN_T; t += PF_D) {
#pragma unroll
        for (int j = 0; j < PF_D; ++j) {
            const f32x2 xc = buf[j];
            int tn = t + j + PF_D;
            tn = tn < RNN_T ? tn : RNN_T - 1;
            buf[j] = __builtin_nontemporal_load(xp + (size_t)tn * RNN_PG2);

            hx = fast_tanh(fmaf(wi.x, xc.x, fmaf(wh.x, hx, bias_x)));
            hy = fast_tanh(fmaf(wi.y, xc.y, fmaf(wh.y, hy, bias_y)));

            f32x2 h2; h2.x = hx; h2.y = hy;
            __builtin_nontemporal_store(h2, op + (size_t)(t + j) * RNN_PG2);
        }
    }
}

extern "C" void kernel_launch(void* const* d_in, const int* in_sizes, int n_in,
                              void* d_out, int out_size, void* d_ws, size_t ws_size,
                              hipStream_t stream) {
    const float* x    = (const float*)d_in[0];
    const float* w_ih = (const float*)d_in[1];
    const float* w_hh = (const float*)d_in[2];
    const float* b_ih = (const float*)d_in[3];
    const float* b_hh = (const float*)d_in[4];
    float* out        = (float*)d_out;

    // B*PG2 = 131072 threads -> 512 blocks x 256 (2 blocks/CU, 8 waves/CU).
    pixel_rnn_kernel<<<dim3(RNN_B * RNN_PG2 / 256), dim3(256), 0, stream>>>(
        x, w_ih, w_hh, b_ih, b_hh, out);
}